// Round 3
// baseline (582.809 us; speedup 1.0000x reference)
//
#include <hip/hip_runtime.h>
#include <hip/hip_bf16.h>

#define NN 100000
#define EE 1600000
#define ET (EE + NN)
#define NBK 391           // dst buckets of 256 nodes: ceil(100000/256)
#define NBLK 208          // binning blocks: ceil(ET/8192)
#define STAGE_CAP 4096    // LDS pair stage per bucket (mean ~4350; overflow re-reads L2)

typedef unsigned short ushort_t;
typedef short short8 __attribute__((ext_vector_type(8)));
typedef float f32x4 __attribute__((ext_vector_type(4)));

static __device__ __forceinline__ float b2f(unsigned short u) {
    return __uint_as_float(((unsigned int)u) << 16);
}
static __device__ __forceinline__ unsigned short f2b(float f) {
    unsigned int x = __float_as_uint(f);
    return (unsigned short)((x + 0x7fffu + ((x >> 16) & 1u)) >> 16);
}

// ---------------- GEMM1 body (shared by kfuse1/kfuse2): h1[row0..row0+64) = x @ W1
static __device__ void gemm1_body(const float* __restrict__ x,
                                  const ushort_t* __restrict__ w1t,
                                  ushort_t* __restrict__ h1,
                                  char* smem_, int row0, int tid) {
    ushort_t (*xs)[136] = (ushort_t (*)[136])smem_;
    const int wid = tid >> 6, lane = tid & 63;
    const int l15 = lane & 15, qq = lane >> 4;
    f32x4 acc[4];
#pragma unroll
    for (int i = 0; i < 4; ++i) acc[i] = (f32x4)0.f;
    for (int kc = 0; kc < 4; ++kc) {
        float4 f[8];
#pragma unroll
        for (int i = 0; i < 8; ++i) {
            int f4i = tid + 256 * i;
            int rr = f4i >> 5;
            int cc = f4i & 31;
            long gr = (long)min(row0 + rr, NN - 1);
            f[i] = *(const float4*)(x + gr * 512 + kc * 128 + cc * 4);
        }
        __syncthreads();
#pragma unroll
        for (int i = 0; i < 8; ++i) {
            int f4i = tid + 256 * i;
            int rr = f4i >> 5, cc = f4i & 31;
            uint2 uu;
            uu.x = ((unsigned)f2b(f[i].y) << 16) | f2b(f[i].x);
            uu.y = ((unsigned)f2b(f[i].w) << 16) | f2b(f[i].z);
            *(uint2*)&xs[rr][cc * 4] = uu;
        }
        __syncthreads();
#pragma unroll
        for (int ks = 0; ks < 4; ++ks) {
            short8 b = *(const short8*)(w1t + (size_t)(wid * 16 + l15) * 512 + kc * 128 + ks * 32 + qq * 8);
#pragma unroll
            for (int mt = 0; mt < 4; ++mt) {
                short8 a = *(const short8*)&xs[mt * 16 + l15][ks * 32 + qq * 8];
                acc[mt] = __builtin_amdgcn_mfma_f32_16x16x32_bf16(a, b, acc[mt], 0, 0, 0);
            }
        }
    }
#pragma unroll
    for (int mt = 0; mt < 4; ++mt) {
        int node = row0 + mt * 16 + qq * 4;
#pragma unroll
        for (int rr = 0; rr < 4; ++rr) {
            if (node + rr < NN)
                h1[(size_t)(node + rr) * 64 + wid * 16 + l15] = f2b(acc[mt][rr]);
        }
    }
}

// ---------------- fused: weight transpose (160 blocks) || coarse histogram (208 blocks)
__global__ __launch_bounds__(256) void kfuse0(const float* __restrict__ W1,
                                              const float* __restrict__ W2,
                                              ushort_t* __restrict__ W1T,
                                              ushort_t* __restrict__ W2T,
                                              const int* __restrict__ ei,
                                              int* __restrict__ bbcnt) {
    __shared__ int hist[NBK];
    const int t = threadIdx.x;
    if ((int)blockIdx.x < 160) {
        int tid = blockIdx.x * 256 + t;
        if (tid < 32768) {
            int k = tid >> 6, c = tid & 63;
            W1T[c * 512 + k] = f2b(W1[tid]);
        } else if (tid < 40960) {
            int q = tid - 32768;
            int k = q >> 7, c = q & 127;
            W2T[c * 64 + k] = f2b(W2[q]);
        }
    } else {
        const int blk = blockIdx.x - 160;
        for (int i = t; i < NBK; i += 256) hist[i] = 0;
        __syncthreads();
        const int e0 = blk * 8192;
#pragma unroll
        for (int i = 0; i < 32; ++i) {
            int e = e0 + t + 256 * i;
            if (e < ET) {
                int dst = (e < EE) ? ei[EE + e] : (e - EE);
                atomicAdd(&hist[dst >> 8], 1);
            }
        }
        __syncthreads();
        for (int i = t; i < NBK; i += 256) bbcnt[blk * NBK + i] = hist[i];
    }
}

// ---------------- in-place exclusive scan of bbcnt per bucket + bucket bases
__global__ __launch_bounds__(512) void kbscan(int* __restrict__ bbcnt,
                                              int* __restrict__ bbase) {
    __shared__ int tot[512];
    const int t = threadIdx.x;
    int total = 0;
    if (t < NBK) {
        int run = 0;
#pragma unroll 8
        for (int blk = 0; blk < NBLK; ++blk) {
            int idx = blk * NBK + t;
            int v = bbcnt[idx];
            bbcnt[idx] = run;
            run += v;
        }
        total = run;
    }
    tot[t] = total;
    __syncthreads();
    for (int off = 1; off < 512; off <<= 1) {
        int u = (t >= off) ? tot[t - off] : 0;
        __syncthreads();
        tot[t] += u;
        __syncthreads();
    }
    if (t < NBK) bbase[t] = tot[t] - total;  // exclusive
    if (t == 0) bbase[NBK] = ET;
}

// ---------------- fused: pair-binning scatter (208 blocks) || gemm1 first half (782 blocks)
__global__ __launch_bounds__(256) void kfuse1(const int* __restrict__ ei,
                                              const int* __restrict__ bbcnt,
                                              const int* __restrict__ bbase,
                                              unsigned* __restrict__ pairs,
                                              const float* __restrict__ x,
                                              const ushort_t* __restrict__ w1t,
                                              ushort_t* __restrict__ h1) {
    __shared__ __align__(16) char smem[17408];
    const int t = threadIdx.x;
    if ((int)blockIdx.x < NBLK) {
        int* cur = (int*)smem;
        const int blk = blockIdx.x;
        for (int i = t; i < NBK; i += 256) cur[i] = bbase[i] + bbcnt[blk * NBK + i];
        __syncthreads();
        const int e0 = blk * 8192;
#pragma unroll
        for (int i = 0; i < 32; ++i) {
            int e = e0 + t + 256 * i;
            if (e < ET) {
                int src, dst;
                if (e < EE) { src = ei[e]; dst = ei[EE + e]; } else { src = dst = e - EE; }
                int pos = atomicAdd(&cur[dst >> 8], 1);
                pairs[pos] = (unsigned)src | ((unsigned)(dst & 255) << 17);
            }
        }
    } else {
        gemm1_body(x, w1t, h1, smem, (blockIdx.x - NBLK) * 64, t);
    }
}

// ---------------- fused: per-bucket sort+rowp (391 blocks) || gemm1 second half (781 blocks)
__global__ __launch_bounds__(256) void kfuse2(const int* __restrict__ bbase,
                                              const unsigned* __restrict__ pairs,
                                              int* __restrict__ rowp,
                                              int* __restrict__ srt,
                                              const float* __restrict__ x,
                                              const ushort_t* __restrict__ w1t,
                                              ushort_t* __restrict__ h1) {
    __shared__ __align__(16) char smem[19456];
    const int t = threadIdx.x;
    if ((int)blockIdx.x < NBK) {
        int* hist = (int*)smem;
        int* scn = hist + 256;
        int* cur = scn + 256;
        unsigned* stage = (unsigned*)(smem + 3072);
        const int b = blockIdx.x;
        const int j0 = bbase[b], j1 = bbase[b + 1];
        const int cnt = j1 - j0;
        hist[t] = 0;
        __syncthreads();
        for (int i = t; i < cnt; i += 256) {
            unsigned p = pairs[j0 + i];
            if (i < STAGE_CAP) stage[i] = p;
            atomicAdd(&hist[p >> 17], 1);
        }
        __syncthreads();
        const int h = hist[t];
        scn[t] = h;
        __syncthreads();
        for (int off = 1; off < 256; off <<= 1) {
            int u = (t >= off) ? scn[t - off] : 0;
            __syncthreads();
            scn[t] += u;
            __syncthreads();
        }
        const int pref = scn[t] - h;  // exclusive prefix within bucket
        const int node = b * 256 + t;
        if (node < NN) rowp[node] = j0 + pref;
        if (b == 0 && t == 0) rowp[NN] = ET;
        cur[t] = pref;
        __syncthreads();
        for (int i = t; i < cnt; i += 256) {
            unsigned p = (i < STAGE_CAP) ? stage[i] : pairs[j0 + i];
            int l = (int)(p >> 17);
            int pos = atomicAdd(&cur[l], 1);
            srt[j0 + pos] = (int)(p & 0x1FFFFu);
        }
    } else {
        gemm1_body(x, w1t, h1, smem, (782 + (int)blockIdx.x - NBK) * 64, t);
    }
}

// ---------------- alpha precompute, layer 1: a1s/a1d[n,h] = h1[n,h*8..]·aws/awd
__global__ __launch_bounds__(256) void kalpha1(const ushort_t* __restrict__ h1,
                                               const float* __restrict__ aws,
                                               const float* __restrict__ awd,
                                               float* __restrict__ a1s,
                                               float* __restrict__ a1d) {
    int tid = blockIdx.x * 256 + threadIdx.x;  // exactly N*8
    int n = tid >> 3, h = tid & 7;
    uint4 v = *(const uint4*)(h1 + (size_t)n * 64 + h * 8);
    const ushort_t* p = (const ushort_t*)&v;
    float s = 0.f, d = 0.f;
#pragma unroll
    for (int c = 0; c < 8; ++c) {
        float f = b2f(p[c]);
        s += f * aws[h * 8 + c];
        d += f * awd[h * 8 + c];
    }
    a1s[tid] = s;
    a1d[tid] = d;
}

// ---------------- alpha precompute, layer 2: a2s/a2d[n,h] = h2[n,h*16..]·aws/awd
__global__ __launch_bounds__(256) void kalpha2(const ushort_t* __restrict__ h2,
                                               const float* __restrict__ aws,
                                               const float* __restrict__ awd,
                                               float* __restrict__ a2s,
                                               float* __restrict__ a2d) {
    int tid = blockIdx.x * 256 + threadIdx.x;  // exactly N*8
    int n = tid >> 3, h = tid & 7;
    uint4 v0 = *(const uint4*)(h2 + (size_t)n * 128 + h * 16);
    uint4 v1 = *(const uint4*)(h2 + (size_t)n * 128 + h * 16 + 8);
    const ushort_t* p0 = (const ushort_t*)&v0;
    const ushort_t* p1 = (const ushort_t*)&v1;
    float s = 0.f, d = 0.f;
#pragma unroll
    for (int c = 0; c < 8; ++c) {
        float fa = b2f(p0[c]), fb = b2f(p1[c]);
        s += fa * aws[h * 16 + c];
        d += fa * awd[h * 16 + c];
        s += fb * aws[h * 16 + 8 + c];
        d += fb * awd[h * 16 + 8 + c];
    }
    a2s[tid] = s;
    a2d[tid] = d;
}

// ================= layer-1 fused agg: 2-way edge-split, precomputed alphas, pipelined gather
__global__ __launch_bounds__(256) void kagg1(const int* __restrict__ rowp,
                                             const int* __restrict__ srt,
                                             const ushort_t* __restrict__ h1,
                                             const float* __restrict__ a1s,
                                             const float* __restrict__ a1d,
                                             const float* __restrict__ b1,
                                             const float* __restrict__ pw,
                                             ushort_t* __restrict__ hin) {
    int tid = blockIdx.x * 256 + threadIdx.x;  // exactly N*16
    int n = tid >> 4;
    int sub = tid & 15;
    int h = sub >> 1, half = sub & 1;
    float ad = a1d[n * 8 + h];
    int j0 = rowp[n], j1 = rowp[n + 1];
    float num[8]; float den = 0.f;
#pragma unroll
    for (int c = 0; c < 8; ++c) num[c] = 0.f;
    int j = j0 + half;
    uint4 hv; float al = 0.f;
    if (j < j1) {
        int s = srt[j];
        al = a1s[s * 8 + h];
        hv = *(const uint4*)(h1 + (size_t)s * 64 + h * 8);
    }
    while (j < j1) {
        int jn = j + 2;
        uint4 hn; float aln = 0.f;
        if (jn < j1) {
            int sn = srt[jn];
            aln = a1s[sn * 8 + h];
            hn = *(const uint4*)(h1 + (size_t)sn * 64 + h * 8);
        }
        float sc = al + ad;
        sc = (sc >= 0.f) ? sc : 0.2f * sc;
        float w = __expf(sc);
        den += w;
        const ushort_t* hp = (const ushort_t*)&hv;
#pragma unroll
        for (int c = 0; c < 8; ++c) num[c] += w * b2f(hp[c]);
        j = jn;
        hv = hn;
        al = aln;
    }
#pragma unroll
    for (int c = 0; c < 8; ++c) num[c] += __shfl_xor(num[c], 1);
    den += __shfl_xor(den, 1);
    if (half == 0) {
        float inv = 1.f / den;  // den > 0 (self-loop guarantees >=1 edge)
        float pwf = pw[0];
        ushort_t o[8];
#pragma unroll
        for (int c = 0; c < 8; ++c) {
            float v = num[c] * inv + b1[h * 8 + c];
            v = (v >= 0.f) ? v : pwf * v;
            o[c] = f2b(v);
        }
        *(uint4*)(hin + (size_t)n * 64 + h * 8) = *(uint4*)o;
    }
}

// ---------------- GEMM2: h2[N,128] = hin[N,64] @ W2  (bf16 in/out)
__global__ __launch_bounds__(256) void kgemm2(const ushort_t* __restrict__ hin,
                                              const ushort_t* __restrict__ w2t,
                                              ushort_t* __restrict__ h2) {
    __shared__ __align__(16) ushort_t xs[64][72];
    const int tid = threadIdx.x;
    const int wid = tid >> 6, lane = tid & 63;
    const int l15 = lane & 15, qq = lane >> 4;
    const int row0 = blockIdx.x * 64;
    const int r = tid >> 2, seg = tid & 3;
    const long grow = (long)min(row0 + r, NN - 1);
    const uint4* gp = (const uint4*)(hin + grow * 64 + seg * 16);
    uint4 v0 = gp[0], v1 = gp[1];
    uint4* lp = (uint4*)&xs[r][seg * 16];
    lp[0] = v0; lp[1] = v1;
    __syncthreads();
    f32x4 acc[4][2];
#pragma unroll
    for (int i = 0; i < 4; ++i)
#pragma unroll
        for (int j = 0; j < 2; ++j) acc[i][j] = (f32x4)0.f;
#pragma unroll
    for (int ks = 0; ks < 2; ++ks) {
        short8 a[4];
#pragma unroll
        for (int mt = 0; mt < 4; ++mt)
            a[mt] = *(const short8*)&xs[mt * 16 + l15][ks * 32 + qq * 8];
#pragma unroll
        for (int nt = 0; nt < 2; ++nt) {
            short8 b = *(const short8*)(w2t + (size_t)(wid * 32 + nt * 16 + l15) * 64 + ks * 32 + qq * 8);
#pragma unroll
            for (int mt = 0; mt < 4; ++mt)
                acc[mt][nt] = __builtin_amdgcn_mfma_f32_16x16x32_bf16(a[mt], b, acc[mt][nt], 0, 0, 0);
        }
    }
#pragma unroll
    for (int mt = 0; mt < 4; ++mt) {
        int node = row0 + mt * 16 + qq * 4;
#pragma unroll
        for (int nt = 0; nt < 2; ++nt) {
            int col = wid * 32 + nt * 16 + l15;
#pragma unroll
            for (int rr = 0; rr < 4; ++rr) {
                if (node + rr < NN)
                    h2[(size_t)(node + rr) * 128 + col] = f2b(acc[mt][nt][rr]);
            }
        }
    }
}

// ================= layer-2 fused agg: 2-way edge-split, precomputed alphas,
// head-mean via LDS, log_softmax. 16 nodes per block (grid 6250*16 == NN exactly).
__global__ __launch_bounds__(256) void kagg2(const int* __restrict__ rowp,
                                             const int* __restrict__ srt,
                                             const ushort_t* __restrict__ h2,
                                             const float* __restrict__ a2s,
                                             const float* __restrict__ a2d,
                                             const float* __restrict__ b2,
                                             float* __restrict__ out) {
    __shared__ float red[16][17];
    int t = threadIdx.x;
    int nl = t >> 4, sub = t & 15;
    int h = sub >> 1, half = sub & 1;
    int n = blockIdx.x * 16 + nl;
    for (int i = t; i < 16 * 17; i += 256) ((float*)red)[i] = 0.f;
    __syncthreads();
    float ad = a2d[n * 8 + h];
    int j0 = rowp[n], j1 = rowp[n + 1];
    float num[16]; float den = 0.f;
#pragma unroll
    for (int c = 0; c < 16; ++c) num[c] = 0.f;
    int j = j0 + half;
    uint4 v0, v1; float al = 0.f;
    if (j < j1) {
        int s = srt[j];
        al = a2s[s * 8 + h];
        const uint4* rp = (const uint4*)(h2 + (size_t)s * 128 + h * 16);
        v0 = rp[0]; v1 = rp[1];
    }
    while (j < j1) {
        int jn = j + 2;
        uint4 n0, n1; float aln = 0.f;
        if (jn < j1) {
            int sn = srt[jn];
            aln = a2s[sn * 8 + h];
            const uint4* rp = (const uint4*)(h2 + (size_t)sn * 128 + h * 16);
            n0 = rp[0]; n1 = rp[1];
        }
        float sc = al + ad;
        sc = (sc >= 0.f) ? sc : 0.2f * sc;
        float w = __expf(sc);
        den += w;
        const ushort_t* p0 = (const ushort_t*)&v0;
        const ushort_t* p1 = (const ushort_t*)&v1;
#pragma unroll
        for (int c = 0; c < 8; ++c) {
            num[c] += w * b2f(p0[c]);
            num[8 + c] += w * b2f(p1[c]);
        }
        j = jn;
        v0 = n0; v1 = n1;
        al = aln;
    }
#pragma unroll
    for (int c = 0; c < 16; ++c) num[c] += __shfl_xor(num[c], 1);
    den += __shfl_xor(den, 1);
    float sden = 0.125f / den;
#pragma unroll
    for (int k = 0; k < 8; ++k) {
        int c = half * 8 + ((h + k) & 7);
        atomicAdd(&red[nl][c], num[c] * sden);
    }
    __syncthreads();
    if (t < 16) {
        float v[16];
#pragma unroll
        for (int d = 0; d < 16; ++d) v[d] = red[t][d] + b2[d];
        float m = v[0];
#pragma unroll
        for (int d = 1; d < 16; ++d) m = fmaxf(m, v[d]);
        float sum = 0.f;
#pragma unroll
        for (int d = 0; d < 16; ++d) sum += __expf(v[d] - m);
        float ls = __logf(sum) + m;
        float* op = out + (size_t)(blockIdx.x * 16 + t) * 16;
#pragma unroll
        for (int d = 0; d < 16; ++d) op[d] = v[d] - ls;
    }
}

extern "C" void kernel_launch(void* const* d_in, const int* in_sizes, int n_in,
                              void* d_out, int out_size, void* d_ws, size_t ws_size,
                              hipStream_t stream) {
    const float* x    = (const float*)d_in[0];
    const int*   ei   = (const int*)d_in[1];
    const float* W1   = (const float*)d_in[2];
    const float* aws1 = (const float*)d_in[3];
    const float* awd1 = (const float*)d_in[4];
    const float* b1   = (const float*)d_in[5];
    const float* pw   = (const float*)d_in[6];
    const float* W2   = (const float*)d_in[7];
    const float* aws2 = (const float*)d_in[8];
    const float* awd2 = (const float*)d_in[9];
    const float* b2   = (const float*)d_in[10];
    float* out = (float*)d_out;

    // Arena (46.5 MB peak):
    //   [ 0.0 -  6.8M) sorted_src (ET int)
    //   [ 6.8 -  7.2M) row_ptr (N+1 int)
    //   [ 7.2 -  7.53M) bbcnt table (NBLK x NBK int)
    //   [ 7.6M +1.6K ) bbase (NBK+1 int)
    //   [ 8.0 - 14.8M) pairs (ET u32)      [dead after kfuse2]
    //   [ 8.0 - 20.8M) hin (bf16)          [written by kagg1, read by kgemm2, dead after]
    //   [ 8.0 - 11.2M) a2s                 [over dead hin, written by kalpha2]
    //   [11.2 - 14.4M) a2d                 [over dead hin]
    //   [20.8 - 33.6M) h1 (bf16)           [dead after kagg1]
    //   [33.6 - 36.8M) a1s                 [in h2 tail, dead before kgemm2 writes h2]
    //   [36.8 - 40.0M) a1d
    //   [20.8 - 46.4M) h2 (bf16)           [overlaps dead h1/a1s/a1d; written by kgemm2]
    //   [46.4M+) W1T (64KB), W2T (16KB)
    char* ws = (char*)d_ws;
    int*      srt   = (int*)(ws + 0);
    int*      rowp  = (int*)(ws + 6800000);
    int*      bbcnt = (int*)(ws + 7200256);
    int*      bbase = (int*)(ws + 7600384);
    unsigned* pairs = (unsigned*)(ws + 8000000);
    ushort_t* hin   = (ushort_t*)(ws + 8000000);
    float*    a2s   = (float*)(ws + 8000000);
    float*    a2d   = (float*)(ws + 11200000);
    ushort_t* h1    = (ushort_t*)(ws + 20800000);
    ushort_t* h2    = (ushort_t*)(ws + 20800000);
    float*    a1s   = (float*)(ws + 33600000);
    float*    a1d   = (float*)(ws + 36800000);
    ushort_t* W1T   = (ushort_t*)(ws + 46400000);
    ushort_t* W2T   = (ushort_t*)(ws + 46465536);

    kfuse0<<<160 + NBLK, 256, 0, stream>>>(W1, W2, W1T, W2T, ei, bbcnt);
    kbscan<<<1, 512, 0, stream>>>(bbcnt, bbase);
    kfuse1<<<NBLK + 782, 256, 0, stream>>>(ei, bbcnt, bbase, pairs, x, W1T, h1);
    kfuse2<<<NBK + 781, 256, 0, stream>>>(bbase, pairs, rowp, srt, x, W1T, h1);
    kalpha1<<<3125, 256, 0, stream>>>(h1, aws1, awd1, a1s, a1d);
    kagg1<<<6250, 256, 0, stream>>>(rowp, srt, h1, a1s, a1d, b1, pw, hin);
    kgemm2<<<1563, 256, 0, stream>>>(hin, W2T, h2);
    kalpha2<<<3125, 256, 0, stream>>>(h2, aws2, awd2, a2s, a2d);
    kagg2<<<6250, 256, 0, stream>>>(rowp, srt, h2, a2s, a2d, b2, out);
}

// Round 4
// 502.549 us; speedup vs baseline: 1.1597x; 1.1597x over previous
//
#include <hip/hip_runtime.h>
#include <hip/hip_bf16.h>

#define NN 100000
#define EE 1600000
#define ET (EE + NN)
#define NBK 391           // dst buckets of 256 nodes: ceil(100000/256)
#define NBLK 208          // binning blocks: ceil(ET/8192)
#define STAGE_CAP 4096    // LDS pair stage per bucket (mean ~4350; overflow re-reads L2)

typedef unsigned short ushort_t;
typedef short short8 __attribute__((ext_vector_type(8)));
typedef float f32x4 __attribute__((ext_vector_type(4)));

static __device__ __forceinline__ float b2f(unsigned short u) {
    return __uint_as_float(((unsigned int)u) << 16);
}
static __device__ __forceinline__ unsigned short f2b(float f) {
    unsigned int x = __float_as_uint(f);
    return (unsigned short)((x + 0x7fffu + ((x >> 16) & 1u)) >> 16);
}

// ---------------- GEMM1 body (shared by kfuse1/kfuse2): h1[row0..row0+64) = x @ W1
static __device__ void gemm1_body(const float* __restrict__ x,
                                  const ushort_t* __restrict__ w1t,
                                  ushort_t* __restrict__ h1,
                                  char* smem_, int row0, int tid) {
    ushort_t (*xs)[136] = (ushort_t (*)[136])smem_;
    const int wid = tid >> 6, lane = tid & 63;
    const int l15 = lane & 15, qq = lane >> 4;
    f32x4 acc[4];
#pragma unroll
    for (int i = 0; i < 4; ++i) acc[i] = (f32x4)0.f;
    for (int kc = 0; kc < 4; ++kc) {
        float4 f[8];
#pragma unroll
        for (int i = 0; i < 8; ++i) {
            int f4i = tid + 256 * i;
            int rr = f4i >> 5;
            int cc = f4i & 31;
            long gr = (long)min(row0 + rr, NN - 1);
            f[i] = *(const float4*)(x + gr * 512 + kc * 128 + cc * 4);
        }
        __syncthreads();
#pragma unroll
        for (int i = 0; i < 8; ++i) {
            int f4i = tid + 256 * i;
            int rr = f4i >> 5, cc = f4i & 31;
            uint2 uu;
            uu.x = ((unsigned)f2b(f[i].y) << 16) | f2b(f[i].x);
            uu.y = ((unsigned)f2b(f[i].w) << 16) | f2b(f[i].z);
            *(uint2*)&xs[rr][cc * 4] = uu;
        }
        __syncthreads();
#pragma unroll
        for (int ks = 0; ks < 4; ++ks) {
            short8 b = *(const short8*)(w1t + (size_t)(wid * 16 + l15) * 512 + kc * 128 + ks * 32 + qq * 8);
#pragma unroll
            for (int mt = 0; mt < 4; ++mt) {
                short8 a = *(const short8*)&xs[mt * 16 + l15][ks * 32 + qq * 8];
                acc[mt] = __builtin_amdgcn_mfma_f32_16x16x32_bf16(a, b, acc[mt], 0, 0, 0);
            }
        }
    }
#pragma unroll
    for (int mt = 0; mt < 4; ++mt) {
        int node = row0 + mt * 16 + qq * 4;
#pragma unroll
        for (int rr = 0; rr < 4; ++rr) {
            if (node + rr < NN)
                h1[(size_t)(node + rr) * 64 + wid * 16 + l15] = f2b(acc[mt][rr]);
        }
    }
}

// ---------------- fused: weight transpose (160 blocks) || coarse histogram (208 blocks)
__global__ __launch_bounds__(256) void kfuse0(const float* __restrict__ W1,
                                              const float* __restrict__ W2,
                                              ushort_t* __restrict__ W1T,
                                              ushort_t* __restrict__ W2T,
                                              const int* __restrict__ ei,
                                              int* __restrict__ bbcnt) {
    __shared__ int hist[NBK];
    const int t = threadIdx.x;
    if ((int)blockIdx.x < 160) {
        int tid = blockIdx.x * 256 + t;
        if (tid < 32768) {
            int k = tid >> 6, c = tid & 63;
            W1T[c * 512 + k] = f2b(W1[tid]);
        } else if (tid < 40960) {
            int q = tid - 32768;
            int k = q >> 7, c = q & 127;
            W2T[c * 64 + k] = f2b(W2[q]);
        }
    } else {
        const int blk = blockIdx.x - 160;
        for (int i = t; i < NBK; i += 256) hist[i] = 0;
        __syncthreads();
        const int e0 = blk * 8192;
#pragma unroll
        for (int i = 0; i < 32; ++i) {
            int e = e0 + t + 256 * i;
            if (e < ET) {
                int dst = (e < EE) ? ei[EE + e] : (e - EE);
                atomicAdd(&hist[dst >> 8], 1);
            }
        }
        __syncthreads();
        for (int i = t; i < NBK; i += 256) bbcnt[blk * NBK + i] = hist[i];
    }
}

// ---------------- in-place exclusive scan of bbcnt per bucket + bucket bases
__global__ __launch_bounds__(512) void kbscan(int* __restrict__ bbcnt,
                                              int* __restrict__ bbase) {
    __shared__ int tot[512];
    const int t = threadIdx.x;
    int total = 0;
    if (t < NBK) {
        int run = 0;
#pragma unroll 8
        for (int blk = 0; blk < NBLK; ++blk) {
            int idx = blk * NBK + t;
            int v = bbcnt[idx];
            bbcnt[idx] = run;
            run += v;
        }
        total = run;
    }
    tot[t] = total;
    __syncthreads();
    for (int off = 1; off < 512; off <<= 1) {
        int u = (t >= off) ? tot[t - off] : 0;
        __syncthreads();
        tot[t] += u;
        __syncthreads();
    }
    if (t < NBK) bbase[t] = tot[t] - total;  // exclusive
    if (t == 0) bbase[NBK] = ET;
}

// ---------------- fused: pair-binning scatter (208 blocks) || gemm1 first half (782 blocks)
__global__ __launch_bounds__(256) void kfuse1(const int* __restrict__ ei,
                                              const int* __restrict__ bbcnt,
                                              const int* __restrict__ bbase,
                                              unsigned* __restrict__ pairs,
                                              const float* __restrict__ x,
                                              const ushort_t* __restrict__ w1t,
                                              ushort_t* __restrict__ h1) {
    __shared__ __align__(16) char smem[17408];
    const int t = threadIdx.x;
    if ((int)blockIdx.x < NBLK) {
        int* cur = (int*)smem;
        const int blk = blockIdx.x;
        for (int i = t; i < NBK; i += 256) cur[i] = bbase[i] + bbcnt[blk * NBK + i];
        __syncthreads();
        const int e0 = blk * 8192;
#pragma unroll
        for (int i = 0; i < 32; ++i) {
            int e = e0 + t + 256 * i;
            if (e < ET) {
                int src, dst;
                if (e < EE) { src = ei[e]; dst = ei[EE + e]; } else { src = dst = e - EE; }
                int pos = atomicAdd(&cur[dst >> 8], 1);
                pairs[pos] = (unsigned)src | ((unsigned)(dst & 255) << 17);
            }
        }
    } else {
        gemm1_body(x, w1t, h1, smem, (blockIdx.x - NBLK) * 64, t);
    }
}

// ---------------- fused: per-bucket sort+rowp (391 blocks) || gemm1 second half (781 blocks)
__global__ __launch_bounds__(256) void kfuse2(const int* __restrict__ bbase,
                                              const unsigned* __restrict__ pairs,
                                              int* __restrict__ rowp,
                                              int* __restrict__ srt,
                                              const float* __restrict__ x,
                                              const ushort_t* __restrict__ w1t,
                                              ushort_t* __restrict__ h1) {
    __shared__ __align__(16) char smem[19456];
    const int t = threadIdx.x;
    if ((int)blockIdx.x < NBK) {
        int* hist = (int*)smem;
        int* scn = hist + 256;
        int* cur = scn + 256;
        unsigned* stage = (unsigned*)(smem + 3072);
        const int b = blockIdx.x;
        const int j0 = bbase[b], j1 = bbase[b + 1];
        const int cnt = j1 - j0;
        hist[t] = 0;
        __syncthreads();
        for (int i = t; i < cnt; i += 256) {
            unsigned p = pairs[j0 + i];
            if (i < STAGE_CAP) stage[i] = p;
            atomicAdd(&hist[p >> 17], 1);
        }
        __syncthreads();
        const int h = hist[t];
        scn[t] = h;
        __syncthreads();
        for (int off = 1; off < 256; off <<= 1) {
            int u = (t >= off) ? scn[t - off] : 0;
            __syncthreads();
            scn[t] += u;
            __syncthreads();
        }
        const int pref = scn[t] - h;  // exclusive prefix within bucket
        const int node = b * 256 + t;
        if (node < NN) rowp[node] = j0 + pref;
        if (b == 0 && t == 0) rowp[NN] = ET;
        cur[t] = pref;
        __syncthreads();
        for (int i = t; i < cnt; i += 256) {
            unsigned p = (i < STAGE_CAP) ? stage[i] : pairs[j0 + i];
            int l = (int)(p >> 17);
            int pos = atomicAdd(&cur[l], 1);
            srt[j0 + pos] = (int)(p & 0x1FFFFu);
        }
    } else {
        gemm1_body(x, w1t, h1, smem, (782 + (int)blockIdx.x - NBK) * 64, t);
    }
}

// ================= layer-1 fused agg: 2-way edge-split per (dst,head), inline alpha,
// pipelined gather. thread: node = tid>>4, head = (sub>>1), half = sub&1
__global__ __launch_bounds__(256) void kagg1(const int* __restrict__ rowp,
                                             const int* __restrict__ srt,
                                             const ushort_t* __restrict__ h1,
                                             const float* __restrict__ aws,
                                             const float* __restrict__ awd,
                                             const float* __restrict__ b1,
                                             const float* __restrict__ pw,
                                             ushort_t* __restrict__ hin) {
    int tid = blockIdx.x * 256 + threadIdx.x;  // exactly N*16
    int n = tid >> 4;
    int sub = tid & 15;
    int h = sub >> 1, half = sub & 1;
    float as_w[8], ad_w[8];
#pragma unroll
    for (int c = 0; c < 8; ++c) { as_w[c] = aws[h * 8 + c]; ad_w[c] = awd[h * 8 + c]; }
    uint4 hd = *(const uint4*)(h1 + (size_t)n * 64 + h * 8);
    const ushort_t* hdp = (const ushort_t*)&hd;
    float ad = 0.f;
#pragma unroll
    for (int c = 0; c < 8; ++c) ad += b2f(hdp[c]) * ad_w[c];
    int j0 = rowp[n], j1 = rowp[n + 1];
    float num[8]; float den = 0.f;
#pragma unroll
    for (int c = 0; c < 8; ++c) num[c] = 0.f;
    int j = j0 + half;
    uint4 hv;
    if (j < j1) {
        int s = srt[j];
        hv = *(const uint4*)(h1 + (size_t)s * 64 + h * 8);
    }
    while (j < j1) {
        int jn = j + 2;
        uint4 hn;
        if (jn < j1) {
            int sn = srt[jn];
            hn = *(const uint4*)(h1 + (size_t)sn * 64 + h * 8);
        }
        const ushort_t* hp = (const ushort_t*)&hv;
        float va[8];
#pragma unroll
        for (int c = 0; c < 8; ++c) va[c] = b2f(hp[c]);
        float sc = ad;
#pragma unroll
        for (int c = 0; c < 8; ++c) sc += va[c] * as_w[c];
        sc = (sc >= 0.f) ? sc : 0.2f * sc;
        float w = __expf(sc);
        den += w;
#pragma unroll
        for (int c = 0; c < 8; ++c) num[c] += w * va[c];
        j = jn;
        hv = hn;
    }
    // combine partner halves (lane^1)
#pragma unroll
    for (int c = 0; c < 8; ++c) num[c] += __shfl_xor(num[c], 1);
    den += __shfl_xor(den, 1);
    if (half == 0) {
        float inv = 1.f / den;  // den > 0 (self-loop guarantees >=1 edge)
        float pwf = pw[0];
        ushort_t o[8];
#pragma unroll
        for (int c = 0; c < 8; ++c) {
            float v = num[c] * inv + b1[h * 8 + c];
            v = (v >= 0.f) ? v : pwf * v;
            o[c] = f2b(v);
        }
        *(uint4*)(hin + (size_t)n * 64 + h * 8) = *(uint4*)o;
    }
}

// ---------------- GEMM2: h2[N,128] = hin[N,64] @ W2  (bf16 in/out)
__global__ __launch_bounds__(256) void kgemm2(const ushort_t* __restrict__ hin,
                                              const ushort_t* __restrict__ w2t,
                                              ushort_t* __restrict__ h2) {
    __shared__ __align__(16) ushort_t xs[64][72];
    const int tid = threadIdx.x;
    const int wid = tid >> 6, lane = tid & 63;
    const int l15 = lane & 15, qq = lane >> 4;
    const int row0 = blockIdx.x * 64;
    const int r = tid >> 2, seg = tid & 3;
    const long grow = (long)min(row0 + r, NN - 1);
    const uint4* gp = (const uint4*)(hin + grow * 64 + seg * 16);
    uint4 v0 = gp[0], v1 = gp[1];
    uint4* lp = (uint4*)&xs[r][seg * 16];
    lp[0] = v0; lp[1] = v1;
    __syncthreads();
    f32x4 acc[4][2];
#pragma unroll
    for (int i = 0; i < 4; ++i)
#pragma unroll
        for (int j = 0; j < 2; ++j) acc[i][j] = (f32x4)0.f;
#pragma unroll
    for (int ks = 0; ks < 2; ++ks) {
        short8 a[4];
#pragma unroll
        for (int mt = 0; mt < 4; ++mt)
            a[mt] = *(const short8*)&xs[mt * 16 + l15][ks * 32 + qq * 8];
#pragma unroll
        for (int nt = 0; nt < 2; ++nt) {
            short8 b = *(const short8*)(w2t + (size_t)(wid * 32 + nt * 16 + l15) * 64 + ks * 32 + qq * 8);
#pragma unroll
            for (int mt = 0; mt < 4; ++mt)
                acc[mt][nt] = __builtin_amdgcn_mfma_f32_16x16x32_bf16(a[mt], b, acc[mt][nt], 0, 0, 0);
        }
    }
#pragma unroll
    for (int mt = 0; mt < 4; ++mt) {
        int node = row0 + mt * 16 + qq * 4;
#pragma unroll
        for (int nt = 0; nt < 2; ++nt) {
            int col = wid * 32 + nt * 16 + l15;
#pragma unroll
            for (int rr = 0; rr < 4; ++rr) {
                if (node + rr < NN)
                    h2[(size_t)(node + rr) * 128 + col] = f2b(acc[mt][nt][rr]);
            }
        }
    }
}

// ================= layer-2 fused agg: 2-way edge-split, inline alpha, shuffle head-mean,
// log_softmax. 16 nodes per block, no LDS (grid 6250*16 == NN exactly).
__global__ __launch_bounds__(256) void kagg2(const int* __restrict__ rowp,
                                             const int* __restrict__ srt,
                                             const ushort_t* __restrict__ h2,
                                             const float* __restrict__ aws,
                                             const float* __restrict__ awd,
                                             const float* __restrict__ b2,
                                             float* __restrict__ out) {
    int tid = blockIdx.x * 256 + threadIdx.x;  // exactly N*16
    int n = tid >> 4;
    int sub = tid & 15;
    int h = sub >> 1, half = sub & 1;
    float as_w[16], ad_w[16];
#pragma unroll
    for (int c = 0; c < 16; ++c) { as_w[c] = aws[h * 16 + c]; ad_w[c] = awd[h * 16 + c]; }
    uint4 d0 = *(const uint4*)(h2 + (size_t)n * 128 + h * 16);
    uint4 d1 = *(const uint4*)(h2 + (size_t)n * 128 + h * 16 + 8);
    const ushort_t* dp0 = (const ushort_t*)&d0;
    const ushort_t* dp1 = (const ushort_t*)&d1;
    float ad = 0.f;
#pragma unroll
    for (int c = 0; c < 8; ++c) { ad += b2f(dp0[c]) * ad_w[c]; ad += b2f(dp1[c]) * ad_w[8 + c]; }
    int j0 = rowp[n], j1 = rowp[n + 1];
    float num[16]; float den = 0.f;
#pragma unroll
    for (int c = 0; c < 16; ++c) num[c] = 0.f;
    int j = j0 + half;
    uint4 v0, v1;
    if (j < j1) {
        int s = srt[j];
        const uint4* rp = (const uint4*)(h2 + (size_t)s * 128 + h * 16);
        v0 = rp[0]; v1 = rp[1];
    }
    while (j < j1) {
        int jn = j + 2;
        uint4 n0, n1;
        if (jn < j1) {
            int sn = srt[jn];
            const uint4* rp = (const uint4*)(h2 + (size_t)sn * 128 + h * 16);
            n0 = rp[0]; n1 = rp[1];
        }
        const ushort_t* p0 = (const ushort_t*)&v0;
        const ushort_t* p1 = (const ushort_t*)&v1;
        float va[16];
#pragma unroll
        for (int c = 0; c < 8; ++c) { va[c] = b2f(p0[c]); va[8 + c] = b2f(p1[c]); }
        float sc = ad;
#pragma unroll
        for (int c = 0; c < 16; ++c) sc += va[c] * as_w[c];
        sc = (sc >= 0.f) ? sc : 0.2f * sc;
        float w = __expf(sc);
        den += w;
#pragma unroll
        for (int c = 0; c < 16; ++c) num[c] += w * va[c];
        j = jn;
        v0 = n0; v1 = n1;
    }
    // combine partner halves (lane^1): both halves now hold the per-head totals
#pragma unroll
    for (int c = 0; c < 16; ++c) num[c] += __shfl_xor(num[c], 1);
    den += __shfl_xor(den, 1);
    // pre-scale by per-head softmax denom and head-mean factor
    float sden = 0.125f / den;
    float v[16];
#pragma unroll
    for (int c = 0; c < 16; ++c) v[c] = num[c] * sden;
    // butterfly over the 8 heads (bit0 = half is fixed per parity class -> each head once)
#pragma unroll
    for (int mask = 2; mask <= 8; mask <<= 1)
#pragma unroll
        for (int c = 0; c < 16; ++c) v[c] += __shfl_xor(v[c], mask);
    // all 16 threads of the node now hold the final 16 channels; log_softmax redundantly,
    // each thread writes one float -> one coalesced 64B store per node
#pragma unroll
    for (int c = 0; c < 16; ++c) v[c] += b2[c];
    float m = v[0];
#pragma unroll
    for (int c = 1; c < 16; ++c) m = fmaxf(m, v[c]);
    float sum = 0.f;
#pragma unroll
    for (int c = 0; c < 16; ++c) sum += __expf(v[c] - m);
    float ls = __logf(sum) + m;
    out[(size_t)n * 16 + sub] = v[sub] - ls;
}

extern "C" void kernel_launch(void* const* d_in, const int* in_sizes, int n_in,
                              void* d_out, int out_size, void* d_ws, size_t ws_size,
                              hipStream_t stream) {
    const float* x    = (const float*)d_in[0];
    const int*   ei   = (const int*)d_in[1];
    const float* W1   = (const float*)d_in[2];
    const float* aws1 = (const float*)d_in[3];
    const float* awd1 = (const float*)d_in[4];
    const float* b1   = (const float*)d_in[5];
    const float* pw   = (const float*)d_in[6];
    const float* W2   = (const float*)d_in[7];
    const float* aws2 = (const float*)d_in[8];
    const float* awd2 = (const float*)d_in[9];
    const float* b2   = (const float*)d_in[10];
    float* out = (float*)d_out;

    // Arena (46.5 MB peak):
    //   [ 0.0 -  6.8M) sorted_src (ET int)
    //   [ 6.8 -  7.2M) row_ptr (N+1 int)
    //   [ 7.2 -  7.53M) bbcnt table (NBLK x NBK int)
    //   [ 7.6M +1.6K ) bbase (NBK+1 int)
    //   [ 8.0 - 14.8M) pairs (ET u32)      [dead after kfuse2]
    //   [ 8.0 - 20.8M) hin (bf16)          [written by kagg1, read by kgemm2]
    //   [20.8 - 33.6M) h1 (bf16)           [dead after kagg1]
    //   [20.8 - 46.4M) h2 (bf16)           [overlaps dead h1; written by kgemm2]
    //   [46.4M+) W1T (64KB), W2T (16KB)
    char* ws = (char*)d_ws;
    int*      srt   = (int*)(ws + 0);
    int*      rowp  = (int*)(ws + 6800000);
    int*      bbcnt = (int*)(ws + 7200256);
    int*      bbase = (int*)(ws + 7600384);
    unsigned* pairs = (unsigned*)(ws + 8000000);
    ushort_t* hin   = (ushort_t*)(ws + 8000000);
    ushort_t* h1    = (ushort_t*)(ws + 20800000);
    ushort_t* h2    = (ushort_t*)(ws + 20800000);
    ushort_t* W1T   = (ushort_t*)(ws + 46400000);
    ushort_t* W2T   = (ushort_t*)(ws + 46465536);

    kfuse0<<<160 + NBLK, 256, 0, stream>>>(W1, W2, W1T, W2T, ei, bbcnt);
    kbscan<<<1, 512, 0, stream>>>(bbcnt, bbase);
    kfuse1<<<NBLK + 782, 256, 0, stream>>>(ei, bbcnt, bbase, pairs, x, W1T, h1);
    kfuse2<<<NBK + 781, 256, 0, stream>>>(bbase, pairs, rowp, srt, x, W1T, h1);
    kagg1<<<6250, 256, 0, stream>>>(rowp, srt, h1, aws1, awd1, b1, pw, hin);
    kgemm2<<<1563, 256, 0, stream>>>(hin, W2T, h2);
    kagg2<<<6250, 256, 0, stream>>>(rowp, srt, h2, aws2, awd2, b2, out);
}